// Round 11
// baseline (251.435 us; speedup 1.0000x reference)
//
#include <hip/hip_runtime.h>
#include <hip/hip_bf16.h>

#define E 768
#define HD 64
#define NH 12
#define BSZ 2
#define SEQ 2048
#define M_ROWS (BSZ * SEQ)   // 4096
#define BH (BSZ * NH)        // 24

#define LOG2E 1.44269504f
#define QSCALE 0.18033688f   // 0.125 * log2e folded into Q
#define MSHIFT 16.0f         // fixed exponent shift (scores in log2 domain within +-16)

typedef float f4_t __attribute__((ext_vector_type(4)));
typedef __bf16 bf8_t __attribute__((ext_vector_type(8)));
typedef unsigned short us8_t __attribute__((ext_vector_type(8)));
typedef unsigned short us4_t __attribute__((ext_vector_type(4)));

__device__ inline unsigned short f2bf(float f) {
  union { float f; unsigned u; } v; v.f = f;
  unsigned u = v.u + 0x7FFFu + ((v.u >> 16) & 1u);
  return (unsigned short)(u >> 16);
}

__device__ inline float ex2(float x) { return __builtin_amdgcn_exp2f(x); }

// bf16 pair -> fp32 (low / high halves of a uint)
__device__ inline float bflo(unsigned u) { union { unsigned u; float f; } v; v.u = u << 16; return v.f; }
__device__ inline float bfhi(unsigned u) { union { unsigned u; float f; } v; v.u = u & 0xFFFF0000u; return v.f; }

// pack two fp32 -> two bf16 in one v_perm (round-half-up)
__device__ inline unsigned pk2(float a, float b) {
  union { float f; unsigned u; } ua, ub;
  ua.f = a; ub.f = b;
  return __builtin_amdgcn_perm(ub.u + 0x8000u, ua.u + 0x8000u, 0x07060302u);
}

// ---------------- fused fp32 -> bf16 convert: X, 4 weights, and the MASK -------
// blocks: [0,1536) X | [1536,2688) weights | [2688,6784) mask (8.39M elems)
__global__ __launch_bounds__(256) void cvt_all(
    const float* __restrict__ X, const float* __restrict__ Wq,
    const float* __restrict__ Wk, const float* __restrict__ Wv,
    const float* __restrict__ Wo, const float* __restrict__ mask,
    unsigned short* __restrict__ Xbf, unsigned short* __restrict__ Wqkv,
    unsigned short* __restrict__ Wobf, unsigned short* __restrict__ maskbf) {
  const int nW = E * E;  // 589824
  int id = blockIdx.x;
  const float* src;
  unsigned short* dst;
  float scale = 1.0f;
  int base;
  if (id < 1536) {
    src = X; dst = Xbf; base = id * 2048;
  } else if (id < 2688) {
    int r = id - 1536;
    int k = r / 288;
    int rb = r - k * 288;
    base = rb * 2048;
    if (k == 0)      { src = Wq; dst = Wqkv;          scale = QSCALE; }
    else if (k == 1) { src = Wk; dst = Wqkv + nW;     }
    else if (k == 2) { src = Wv; dst = Wqkv + 2 * nW; }
    else             { src = Wo; dst = Wobf;          }
  } else {
    src = mask; dst = maskbf; base = (id - 2688) * 2048;  // 4096 blocks = 8,388,608 elems
  }
  int i = base + threadIdx.x * 8;
  const float4* s = (const float4*)(src + i);
  float4 a = s[0], b = s[1];
  us8_t o;
  o[0] = f2bf(a.x * scale); o[1] = f2bf(a.y * scale);
  o[2] = f2bf(a.z * scale); o[3] = f2bf(a.w * scale);
  o[4] = f2bf(b.x * scale); o[5] = f2bf(b.y * scale);
  o[6] = f2bf(b.z * scale); o[7] = f2bf(b.w * scale);
  *(us8_t*)(dst + i) = o;
}

// ---------------- fused QKV GEMM: C = X @ Wqkv^T, double-buffered DMA ------
// Q,K written [bh][t][d] (wide 16B stores via per-wave LDS transpose);
// V written TRANSPOSED [bh][d][t].
__global__ __launch_bounds__(256) void gemm_qkv(
    const unsigned short* __restrict__ A, const unsigned short* __restrict__ Bw,
    const float* __restrict__ bq, const float* __restrict__ bk, const float* __restrict__ bv,
    unsigned short* __restrict__ Qb, unsigned short* __restrict__ Kb,
    unsigned short* __restrict__ Vtb) {
  __shared__ unsigned short Alds[2][128 * 32];
  __shared__ unsigned short Blds[2][128 * 32];
  const int w = threadIdx.x >> 6, lane = threadIdx.x & 63;
  const int quad = lane >> 4, l15 = lane & 15;
  const int rowBase = blockIdx.x * 128;
  const int colBase = blockIdx.y * 128;
  const int wr = (w & 1) * 64, wc = (w >> 1) * 64;
  f4_t acc[4][4] = {};

  const int idx0 = (w * 2) * 512 + lane * 8;       // chunk 0 element index
  const int idx1 = (w * 2 + 1) * 512 + lane * 8;   // chunk 1

  // prologue: DMA tile k0=0 into buf 0
#pragma unroll
  for (int c = 0; c < 2; ++c) {
    int idx = (c == 0) ? idx0 : idx1;
    const unsigned short* ga = A + (size_t)(rowBase + (idx >> 5)) * E + (idx & 31);
    __builtin_amdgcn_global_load_lds((const __attribute__((address_space(1))) void*)ga,
        (__attribute__((address_space(3))) void*)&Alds[0][(w * 2 + c) * 512], 16, 0, 0);
    const unsigned short* gb = Bw + (size_t)(colBase + (idx >> 5)) * E + (idx & 31);
    __builtin_amdgcn_global_load_lds((const __attribute__((address_space(1))) void*)gb,
        (__attribute__((address_space(3))) void*)&Blds[0][(w * 2 + c) * 512], 16, 0, 0);
  }
  __builtin_amdgcn_s_waitcnt(0);
  __syncthreads();

  for (int k0 = 0; k0 < E; k0 += 32) {
    const int cur = (k0 >> 5) & 1, nxt = cur ^ 1;
    // issue DMA for k0+32 into the other buffer (hidden under this tile's compute)
    if (k0 + 32 < E) {
#pragma unroll
      for (int c = 0; c < 2; ++c) {
        int idx = (c == 0) ? idx0 : idx1;
        const unsigned short* ga = A + (size_t)(rowBase + (idx >> 5)) * E + k0 + 32 + (idx & 31);
        __builtin_amdgcn_global_load_lds((const __attribute__((address_space(1))) void*)ga,
            (__attribute__((address_space(3))) void*)&Alds[nxt][(w * 2 + c) * 512], 16, 0, 0);
        const unsigned short* gb = Bw + (size_t)(colBase + (idx >> 5)) * E + k0 + 32 + (idx & 31);
        __builtin_amdgcn_global_load_lds((const __attribute__((address_space(1))) void*)gb,
            (__attribute__((address_space(3))) void*)&Blds[nxt][(w * 2 + c) * 512], 16, 0, 0);
      }
    }
    bf8_t af[4], bfr[4];
#pragma unroll
    for (int mi = 0; mi < 4; ++mi)
      af[mi] = *(const bf8_t*)&Alds[cur][(wr + mi * 16 + l15) * 32 + quad * 8];
#pragma unroll
    for (int ni = 0; ni < 4; ++ni)
      bfr[ni] = *(const bf8_t*)&Blds[cur][(wc + ni * 16 + l15) * 32 + quad * 8];
#pragma unroll
    for (int mi = 0; mi < 4; ++mi)
#pragma unroll
      for (int ni = 0; ni < 4; ++ni)
        acc[mi][ni] = __builtin_amdgcn_mfma_f32_16x16x32_bf16(af[mi], bfr[ni], acc[mi][ni], 0, 0, 0);
    __builtin_amdgcn_s_waitcnt(0);  // next-tile DMA landed
    __syncthreads();                // everyone done reading cur
  }

  const int which = colBase / E;
  if (which < 2) {
    const float* biasP = (which == 0) ? bq : bk;
    unsigned short* dst = (which == 0) ? Qb : Kb;
    const float bscale = (which == 0) ? QSCALE : 1.0f;
    const int cnBase = colBase - which * E + wc;  // multiple of 64 -> single head
    const int h = cnBase >> 6;
    float biasv[4];
#pragma unroll
    for (int ni = 0; ni < 4; ++ni) biasv[ni] = biasP[cnBase + ni * 16 + l15] * bscale;
    unsigned short* T = &Alds[0][0] + w * 1024;  // per-wave 16x64 bf16 scratch
    const int row = lane >> 2, colE = (lane & 3) * 16;
#pragma unroll
    for (int mi = 0; mi < 4; ++mi) {
#pragma unroll
      for (int ni = 0; ni < 4; ++ni)
#pragma unroll
        for (int r = 0; r < 4; ++r)
          T[(quad * 4 + r) * 64 + ni * 16 + l15] = f2bf(acc[mi][ni][r] + biasv[ni]);
      us8_t o0 = *(const us8_t*)&T[row * 64 + colE];
      us8_t o1 = *(const us8_t*)&T[row * 64 + colE + 8];
      int gm = rowBase + wr + mi * 16 + row;
      int b = gm >> 11, t = gm & 2047;
      unsigned short* drow = dst + ((size_t)(b * NH + h) * SEQ + t) * HD;
      *(us8_t*)&drow[colE] = o0;
      *(us8_t*)&drow[colE + 8] = o1;
    }
  } else {
    // V^T epilogue: [bh][d][t], 4 consecutive t per store
#pragma unroll
    for (int mi = 0; mi < 4; ++mi) {
#pragma unroll
      for (int ni = 0; ni < 4; ++ni) {
        int cn = colBase - 2 * E + wc + ni * 16 + l15;
        int h = cn >> 6, d = cn & 63;
        float bias = bv[cn];
        int gm0 = rowBase + wr + mi * 16 + quad * 4;
        int b = gm0 >> 11, t = gm0 & 2047;
        us4_t o4;
#pragma unroll
        for (int r = 0; r < 4; ++r) o4[r] = f2bf(acc[mi][ni][r] + bias);
        *(us4_t*)&Vtb[((size_t)(b * NH + h) * HD + d) * SEQ + t] = o4;
      }
    }
  }
}

// ---------------- flash attention v10: 4-wave blocks, no split-S ----------------
// 256 thr = 4 q-subtile waves sharing one 32-iteration s-chain. LDS 24 KB ->
// 5-6 independent blocks/CU (vs 3): barrier groups of 4 waves, double the
// latency-hiding streams. l computed via ones-MFMA (all D rows = row-sum of P^T,
// so l = Lacc[0] per lane, zero shuffles). Grid 768, XCD-swizzled.
__global__ __launch_bounds__(256, 4) void flash_attn10(
    const unsigned short* __restrict__ Qb, const unsigned short* __restrict__ Kb,
    const unsigned short* __restrict__ Vt, const float* __restrict__ biasArr,
    const unsigned short* __restrict__ maskB, const float* __restrict__ betaP,
    unsigned short* __restrict__ attn) {
  __shared__ __align__(16) char smem[24576];
  unsigned short* Klds = (unsigned short*)smem;            // [4096] = 8 KB
  unsigned short* Vlds = (unsigned short*)(smem + 8192);   // [4096]
  unsigned short* Plds = (unsigned short*)(smem + 16384);  // [4 wave][1024]
  const int tid = threadIdx.x;
  const int w = tid >> 6, lane = tid & 63;   // w = q-subtile
  const int quad = lane >> 4, l15 = lane & 15;
  const int id = blockIdx.x;
  const int h = id >> 6;            // 0..11
  const int qb = id & 63;
  const int qt = qb >> 1, b = qb & 1;   // XCD = qb%8: 12 heads of (qt,b) share an XCD
  const int bh = b * NH + h;
  const int q0 = qt * 64;
  const int q = q0 + w * 16 + l15;  // this lane's query
  const float betav2 = betaP[0] * LOG2E;
  const int sw = l15 & 7;

  // Q fragment (B-operand of K*Q^T), scores in log2 domain via QSCALE
  const unsigned short* qbase = Qb + ((size_t)bh * SEQ + q) * HD;
  bf8_t qf[2];
  qf[0] = *(const bf8_t*)(qbase + quad * 8);
  qf[1] = *(const bf8_t*)(qbase + 32 + quad * 8);

  // all-ones A fragment for the l row-sum MFMA
  union { us8_t u; bf8_t b; } ou;
#pragma unroll
  for (int i = 0; i < 8; ++i) ou.u[i] = 0x3F80;
  const bf8_t ones = ou.b;

  f4_t Oacc[4] = {};   // unnormalized O^T partial
  f4_t Lacc = {};      // every element converges to l (ones-MFMA)

  unsigned short* Pw = Plds + w * 1024;
  const unsigned short* KgBase = Kb + (size_t)bh * SEQ * HD;
  const unsigned short* VtG = Vt + (size_t)bh * HD * SEQ;
  const unsigned short* maskRow = maskB + ((size_t)b * SEQ + q) * SEQ;
  const float* biasRow = biasArr + (size_t)bh * SEQ;

  // staging geometry: 256 threads stage 64x64 K and V^T tiles, 2 chunks each
  const int e0 = tid * 8;
  const int r0 = e0 >> 6, c0 = e0 & 63;
  const int e1 = 2048 + e0;
  const int r1 = e1 >> 6, c1 = e1 & 63;
  const int ph0 = r0 * 64 + ((((c0 >> 3) ^ (r0 & 7))) << 3);
  const int ph1 = r1 * 64 + ((((c1 >> 3) ^ (r1 & 7))) << 3);

  // ---- prologue: prefetch tile 0 into registers ----
  us8_t kreg[2], vreg[2];
  uint2 mregu[4];
  kreg[0] = *(const us8_t*)(KgBase + (size_t)r0 * HD + c0);
  kreg[1] = *(const us8_t*)(KgBase + (size_t)r1 * HD + c1);
  vreg[0] = *(const us8_t*)(VtG + (size_t)r0 * SEQ + c0);
  vreg[1] = *(const us8_t*)(VtG + (size_t)r1 * SEQ + c1);
#pragma unroll
  for (int st = 0; st < 4; ++st)
    mregu[st] = *(const uint2*)&maskRow[st * 16 + quad * 4];

  for (int it = 0; it < 32; ++it) {
    const int soff = it * 64;
    __syncthreads();  // previous iter's frag reads complete
    *(us8_t*)&Klds[ph0] = kreg[0];
    *(us8_t*)&Klds[ph1] = kreg[1];
    *(us8_t*)&Vlds[ph0] = vreg[0];
    *(us8_t*)&Vlds[ph1] = vreg[1];
    __syncthreads();  // publish staging

    // bias (L2-hot); fold -MSHIFT
    float4 bb[4];
#pragma unroll
    for (int st = 0; st < 4; ++st) {
      float4 b4 = *(const float4*)&biasRow[soff + st * 16 + quad * 4];
      bb[st].x = fmaf(betav2, b4.x, -MSHIFT);
      bb[st].y = fmaf(betav2, b4.y, -MSHIFT);
      bb[st].z = fmaf(betav2, b4.z, -MSHIFT);
      bb[st].w = fmaf(betav2, b4.w, -MSHIFT);
    }

    // S^T = K Q^T (log2 domain)
    f4_t sacc[4];
#pragma unroll
    for (int st = 0; st < 4; ++st) {
      sacc[st] = (f4_t){0.f, 0.f, 0.f, 0.f};
#pragma unroll
      for (int ks = 0; ks < 2; ++ks) {
        bf8_t kf = *(const bf8_t*)&Klds[(st * 16 + l15) * 64 + (((ks * 4 + quad) ^ sw) << 3)];
        sacc[st] = __builtin_amdgcn_mfma_f32_16x16x32_bf16(kf, qf[ks], sacc[st], 0, 0, 0);
      }
    }

    // s += beta*bias*log2e - 16 + mask(bf16)*log2e  (consumes mregu)
#pragma unroll
    for (int st = 0; st < 4; ++st) {
      sacc[st][0] += fmaf(LOG2E, bflo(mregu[st].x), bb[st].x);
      sacc[st][1] += fmaf(LOG2E, bfhi(mregu[st].x), bb[st].y);
      sacc[st][2] += fmaf(LOG2E, bflo(mregu[st].y), bb[st].z);
      sacc[st][3] += fmaf(LOG2E, bfhi(mregu[st].y), bb[st].w);
    }

    // ---- prefetch tile it+1 (best effort) ----
    if (it < 31) {
      const int nf = soff + 64;
      kreg[0] = *(const us8_t*)(KgBase + (size_t)(nf + r0) * HD + c0);
      kreg[1] = *(const us8_t*)(KgBase + (size_t)(nf + r1) * HD + c1);
      vreg[0] = *(const us8_t*)(VtG + (size_t)r0 * SEQ + nf + c0);
      vreg[1] = *(const us8_t*)(VtG + (size_t)r1 * SEQ + nf + c1);
#pragma unroll
      for (int st = 0; st < 4; ++st)
        mregu[st] = *(const uint2*)&maskRow[nf + st * 16 + quad * 4];
    }

    // p = exp2(s); no per-element l accumulation (ones-MFMA handles it)
#pragma unroll
    for (int st = 0; st < 4; ++st)
#pragma unroll
      for (int r = 0; r < 4; ++r) sacc[st][r] = ex2(sacc[st][r]);

    // pack P + per-wave LDS round-trip (swizzled; wave-private, no barrier)
#pragma unroll
    for (int st = 0; st < 4; ++st) {
      uint2 pp;
      pp.x = pk2(sacc[st][0], sacc[st][1]);
      pp.y = pk2(sacc[st][2], sacc[st][3]);
      int col = st * 16 + quad * 4;
      int addr = l15 * 64 + ((((col >> 3) ^ sw)) << 3) + (col & 7);
      *(uint2*)&Pw[addr] = pp;
    }

    // O^T += V^T P^T ; l += ones x P^T
#pragma unroll
    for (int ks = 0; ks < 2; ++ks) {
      bf8_t pf = *(const bf8_t*)&Pw[l15 * 64 + (((ks * 4 + quad) ^ sw) << 3)];
      Lacc = __builtin_amdgcn_mfma_f32_16x16x32_bf16(ones, pf, Lacc, 0, 0, 0);
#pragma unroll
      for (int dt = 0; dt < 4; ++dt) {
        bf8_t vf = *(const bf8_t*)&Vlds[(dt * 16 + l15) * 64 + (((ks * 4 + quad) ^ sw) << 3)];
        Oacc[dt] = __builtin_amdgcn_mfma_f32_16x16x32_bf16(vf, pf, Oacc[dt], 0, 0, 0);
      }
    }
  }

  // every lane: l = Lacc[0] (all D rows identical for ones-A). Direct epilogue.
  float inv = 1.0f / Lacc[0];
  unsigned short* orow = attn + ((size_t)b * SEQ + q) * E + h * HD;
#pragma unroll
  for (int dt = 0; dt < 4; ++dt) {
    us4_t o4;
#pragma unroll
    for (int r = 0; r < 4; ++r) o4[r] = f2bf(Oacc[dt][r] * inv);
    *(us4_t*)&orow[dt * 16 + quad * 4] = o4;
  }
}

// ---------------- output projection GEMM -> fp32 out (64x128, dbuf DMA) --------
__global__ __launch_bounds__(256) void gemm_out(
    const unsigned short* __restrict__ A, const unsigned short* __restrict__ Bw,
    const float* __restrict__ bo, float* __restrict__ out) {
  __shared__ unsigned short Alds[2][64 * 32];
  __shared__ unsigned short Blds[2][128 * 32];
  const int w = threadIdx.x >> 6, lane = threadIdx.x & 63;
  const int quad = lane >> 4, l15 = lane & 15;
  const int rowBase = blockIdx.x * 64;
  const int colBase = blockIdx.y * 128;
  const int wr = (w & 1) * 32, wc = (w >> 1) * 64;
  f4_t acc[2][4] = {};

  const int idxA = w * 512 + lane * 8;
  const int idx0 = (w * 2) * 512 + lane * 8;
  const int idx1 = (w * 2 + 1) * 512 + lane * 8;

  // prologue: DMA tile 0 into buf 0
  {
    const unsigned short* ga = A + (size_t)(rowBase + (idxA >> 5)) * E + (idxA & 31);
    __builtin_amdgcn_global_load_lds((const __attribute__((address_space(1))) void*)ga,
        (__attribute__((address_space(3))) void*)&Alds[0][w * 512], 16, 0, 0);
#pragma unroll
    for (int c = 0; c < 2; ++c) {
      int idx = (c == 0) ? idx0 : idx1;
      const unsigned short* gb = Bw + (size_t)(colBase + (idx >> 5)) * E + (idx & 31);
      __builtin_amdgcn_global_load_lds((const __attribute__((address_space(1))) void*)gb,
          (__attribute__((address_space(3))) void*)&Blds[0][(w * 2 + c) * 512], 16, 0, 0);
    }
  }
  __builtin_amdgcn_s_waitcnt(0);
  __syncthreads();

  for (int k0 = 0; k0 < E; k0 += 32) {
    const int cur = (k0 >> 5) & 1, nxt = cur ^ 1;
    if (k0 + 32 < E) {
      const unsigned short* ga = A + (size_t)(rowBase + (idxA >> 5)) * E + k0 + 32 + (idxA & 31);
      __builtin_amdgcn_global_load_lds((const __attribute__((address_space(1))) void*)ga,
          (__attribute__((address_space(3))) void*)&Alds[nxt][w * 512], 16, 0, 0);
#pragma unroll
      for (int c = 0; c < 2; ++c) {
        int idx = (c == 0) ? idx0 : idx1;
        const unsigned short* gb = Bw + (size_t)(colBase + (idx >> 5)) * E + k0 + 32 + (idx & 31);
        __builtin_amdgcn_global_load_lds((const __attribute__((address_space(1))) void*)gb,
            (__attribute__((address_space(3))) void*)&Blds[nxt][(w * 2 + c) * 512], 16, 0, 0);
      }
    }
    bf8_t af[2], bfr[4];
#pragma unroll
    for (int mi = 0; mi < 2; ++mi)
      af[mi] = *(const bf8_t*)&Alds[cur][(wr + mi * 16 + l15) * 32 + quad * 8];
#pragma unroll
    for (int ni = 0; ni < 4; ++ni)
      bfr[ni] = *(const bf8_t*)&Blds[cur][(wc + ni * 16 + l15) * 32 + quad * 8];
#pragma unroll
    for (int mi = 0; mi < 2; ++mi)
#pragma unroll
      for (int ni = 0; ni < 4; ++ni)
        acc[mi][ni] = __builtin_amdgcn_mfma_f32_16x16x32_bf16(af[mi], bfr[ni], acc[mi][ni], 0, 0, 0);
    __builtin_amdgcn_s_waitcnt(0);
    __syncthreads();
  }

#pragma unroll
  for (int mi = 0; mi < 2; ++mi) {
#pragma unroll
    for (int ni = 0; ni < 4; ++ni) {
      int gn = colBase + wc + ni * 16 + l15;
      float bias = bo[gn];
#pragma unroll
      for (int r = 0; r < 4; ++r) {
        int gm = rowBase + wr + mi * 16 + quad * 4 + r;
        out[(size_t)gm * E + gn] = acc[mi][ni][r] + bias;
      }
    }
  }
}

extern "C" void kernel_launch(void* const* d_in, const int* in_sizes, int n_in,
                              void* d_out, int out_size, void* d_ws, size_t ws_size,
                              hipStream_t stream) {
  const float* hidden = (const float*)d_in[0];
  const float* mask = (const float*)d_in[1];
  const float* abias = (const float*)d_in[2];
  const float* Wq = (const float*)d_in[3];
  const float* bq = (const float*)d_in[4];
  const float* Wk = (const float*)d_in[5];
  const float* bk = (const float*)d_in[6];
  const float* Wv = (const float*)d_in[7];
  const float* bv = (const float*)d_in[8];
  const float* Wo = (const float*)d_in[9];
  const float* bo = (const float*)d_in[10];
  const float* beta = (const float*)d_in[11];
  float* out = (float*)d_out;

  char* ws = (char*)d_ws;
  unsigned short* Xbf = (unsigned short*)(ws);
  unsigned short* Wqkv = (unsigned short*)(ws + 6291456);
  unsigned short* Wobf = (unsigned short*)(ws + 9830400);
  unsigned short* Qbuf = (unsigned short*)(ws + 11010048);
  unsigned short* Kbuf = (unsigned short*)(ws + 17301504);
  unsigned short* Vtb = (unsigned short*)(ws + 23592960);
  unsigned short* Maskbf = (unsigned short*)(ws + 29884416);  // 16.7 MB bytes
  unsigned short* Attn = Xbf;  // Xbf dead after gemm_qkv

  cvt_all<<<6784, 256, 0, stream>>>(hidden, Wq, Wk, Wv, Wo, mask, Xbf, Wqkv, Wobf, Maskbf);
  gemm_qkv<<<dim3(32, 18), 256, 0, stream>>>(Xbf, Wqkv, bq, bk, bv, Qbuf, Kbuf, Vtb);
  flash_attn10<<<768, 256, 0, stream>>>(Qbuf, Kbuf, Vtb, abias, Maskbf, beta, Attn);
  gemm_out<<<dim3(64, 6), 256, 0, stream>>>(Attn, Wobf, bo, out);
}

// Round 12
// 239.409 us; speedup vs baseline: 1.0502x; 1.0502x over previous
//
#include <hip/hip_runtime.h>
#include <hip/hip_bf16.h>

#define E 768
#define HD 64
#define NH 12
#define BSZ 2
#define SEQ 2048
#define M_ROWS (BSZ * SEQ)   // 4096
#define BH (BSZ * NH)        // 24

#define LOG2E 1.44269504f
#define QSCALE 0.18033688f   // 0.125 * log2e folded into Q
#define MSHIFT 16.0f         // fixed exponent shift (scores in log2 domain within +-16)

typedef float f4_t __attribute__((ext_vector_type(4)));
typedef __bf16 bf8_t __attribute__((ext_vector_type(8)));
typedef unsigned short us8_t __attribute__((ext_vector_type(8)));
typedef unsigned short us4_t __attribute__((ext_vector_type(4)));

__device__ inline unsigned short f2bf(float f) {
  union { float f; unsigned u; } v; v.f = f;
  unsigned u = v.u + 0x7FFFu + ((v.u >> 16) & 1u);
  return (unsigned short)(u >> 16);
}

__device__ inline float ex2(float x) { return __builtin_amdgcn_exp2f(x); }

// bf16 pair -> fp32 (low / high halves of a uint)
__device__ inline float bflo(unsigned u) { union { unsigned u; float f; } v; v.u = u << 16; return v.f; }
__device__ inline float bfhi(unsigned u) { union { unsigned u; float f; } v; v.u = u & 0xFFFF0000u; return v.f; }

// pack two fp32 -> two bf16 in one v_perm (round-half-up)
__device__ inline unsigned pk2(float a, float b) {
  union { float f; unsigned u; } ua, ub;
  ua.f = a; ub.f = b;
  return __builtin_amdgcn_perm(ub.u + 0x8000u, ua.u + 0x8000u, 0x07060302u);
}

// ---------------- fused fp32 -> bf16 convert: X, 4 weights, and the MASK -------
// blocks: [0,1536) X | [1536,2688) weights | [2688,6784) mask (8.39M elems)
__global__ __launch_bounds__(256) void cvt_all(
    const float* __restrict__ X, const float* __restrict__ Wq,
    const float* __restrict__ Wk, const float* __restrict__ Wv,
    const float* __restrict__ Wo, const float* __restrict__ mask,
    unsigned short* __restrict__ Xbf, unsigned short* __restrict__ Wqkv,
    unsigned short* __restrict__ Wobf, unsigned short* __restrict__ maskbf) {
  const int nW = E * E;  // 589824
  int id = blockIdx.x;
  const float* src;
  unsigned short* dst;
  float scale = 1.0f;
  int base;
  if (id < 1536) {
    src = X; dst = Xbf; base = id * 2048;
  } else if (id < 2688) {
    int r = id - 1536;
    int k = r / 288;
    int rb = r - k * 288;
    base = rb * 2048;
    if (k == 0)      { src = Wq; dst = Wqkv;          scale = QSCALE; }
    else if (k == 1) { src = Wk; dst = Wqkv + nW;     }
    else if (k == 2) { src = Wv; dst = Wqkv + 2 * nW; }
    else             { src = Wo; dst = Wobf;          }
  } else {
    src = mask; dst = maskbf; base = (id - 2688) * 2048;  // 4096 blocks = 8,388,608 elems
  }
  int i = base + threadIdx.x * 8;
  const float4* s = (const float4*)(src + i);
  float4 a = s[0], b = s[1];
  us8_t o;
  o[0] = f2bf(a.x * scale); o[1] = f2bf(a.y * scale);
  o[2] = f2bf(a.z * scale); o[3] = f2bf(a.w * scale);
  o[4] = f2bf(b.x * scale); o[5] = f2bf(b.y * scale);
  o[6] = f2bf(b.z * scale); o[7] = f2bf(b.w * scale);
  *(us8_t*)(dst + i) = o;
}

// ---------------- fused QKV GEMM: C = X @ Wqkv^T, 64x128 tiles ------
// grid (64, 18) = 1152 blocks (4.5/CU). Wave = 32x64 region, acc[2][4].
// Q,K written [bh][t][d] (wide 16B stores via per-wave LDS transpose);
// V written TRANSPOSED [bh][d][t]. Single-buffered staging (dbuf regressed).
__global__ __launch_bounds__(256) void gemm_qkv(
    const unsigned short* __restrict__ A, const unsigned short* __restrict__ Bw,
    const float* __restrict__ bq, const float* __restrict__ bk, const float* __restrict__ bv,
    unsigned short* __restrict__ Qb, unsigned short* __restrict__ Kb,
    unsigned short* __restrict__ Vtb) {
  __shared__ unsigned short Alds[64 * 32];    // 4 KB
  __shared__ unsigned short Blds[128 * 32];   // 8 KB
  const int w = threadIdx.x >> 6, lane = threadIdx.x & 63;
  const int quad = lane >> 4, l15 = lane & 15;
  const int rowBase = blockIdx.x * 64;
  const int colBase = blockIdx.y * 128;
  const int wr = (w & 1) * 32, wc = (w >> 1) * 64;
  f4_t acc[2][4] = {};

  const int idxA = w * 512 + lane * 8;           // A: 64x32, 1 chunk/wave
  const int idx0 = (w * 2) * 512 + lane * 8;     // B: 128x32, 2 chunks/wave
  const int idx1 = (w * 2 + 1) * 512 + lane * 8;

  for (int k0 = 0; k0 < E; k0 += 32) {
    __syncthreads();
    {
      const unsigned short* ga = A + (size_t)(rowBase + (idxA >> 5)) * E + k0 + (idxA & 31);
      __builtin_amdgcn_global_load_lds((const __attribute__((address_space(1))) void*)ga,
          (__attribute__((address_space(3))) void*)&Alds[w * 512], 16, 0, 0);
    }
#pragma unroll
    for (int c = 0; c < 2; ++c) {
      int idx = (c == 0) ? idx0 : idx1;
      const unsigned short* gb = Bw + (size_t)(colBase + (idx >> 5)) * E + k0 + (idx & 31);
      __builtin_amdgcn_global_load_lds((const __attribute__((address_space(1))) void*)gb,
          (__attribute__((address_space(3))) void*)&Blds[(w * 2 + c) * 512], 16, 0, 0);
    }
    __builtin_amdgcn_s_waitcnt(0);
    __syncthreads();
    bf8_t af[2], bfr[4];
#pragma unroll
    for (int mi = 0; mi < 2; ++mi)
      af[mi] = *(const bf8_t*)&Alds[(wr + mi * 16 + l15) * 32 + quad * 8];
#pragma unroll
    for (int ni = 0; ni < 4; ++ni)
      bfr[ni] = *(const bf8_t*)&Blds[(wc + ni * 16 + l15) * 32 + quad * 8];
#pragma unroll
    for (int mi = 0; mi < 2; ++mi)
#pragma unroll
      for (int ni = 0; ni < 4; ++ni)
        acc[mi][ni] = __builtin_amdgcn_mfma_f32_16x16x32_bf16(af[mi], bfr[ni], acc[mi][ni], 0, 0, 0);
  }

  const int which = colBase / E;
  __syncthreads();  // staging reads done; Blds reusable as transpose scratch
  if (which < 2) {
    const float* biasP = (which == 0) ? bq : bk;
    unsigned short* dst = (which == 0) ? Qb : Kb;
    const float bscale = (which == 0) ? QSCALE : 1.0f;
    const int cnBase = colBase - which * E + wc;  // multiple of 64 -> single head
    const int h = cnBase >> 6;
    float biasv[4];
#pragma unroll
    for (int ni = 0; ni < 4; ++ni) biasv[ni] = biasP[cnBase + ni * 16 + l15] * bscale;
    unsigned short* T = Blds + w * 1024;  // per-wave 16x64 bf16 scratch (Blds = 4096 shorts)
    const int row = lane >> 2, colE = (lane & 3) * 16;
#pragma unroll
    for (int mi = 0; mi < 2; ++mi) {
      // C-fragment -> LDS [t-local][d]
#pragma unroll
      for (int ni = 0; ni < 4; ++ni)
#pragma unroll
        for (int r = 0; r < 4; ++r)
          T[(quad * 4 + r) * 64 + ni * 16 + l15] = f2bf(acc[mi][ni][r] + biasv[ni]);
      // wide re-read: lane owns 32 B of one t row
      us8_t o0 = *(const us8_t*)&T[row * 64 + colE];
      us8_t o1 = *(const us8_t*)&T[row * 64 + colE + 8];
      int gm = rowBase + wr + mi * 16 + row;
      int b = gm >> 11, t = gm & 2047;
      unsigned short* drow = dst + ((size_t)(b * NH + h) * SEQ + t) * HD;
      *(us8_t*)&drow[colE] = o0;
      *(us8_t*)&drow[colE + 8] = o1;
    }
  } else {
    // V^T epilogue: [bh][d][t], 4 consecutive t per store
#pragma unroll
    for (int mi = 0; mi < 2; ++mi) {
#pragma unroll
      for (int ni = 0; ni < 4; ++ni) {
        int cn = colBase - 2 * E + wc + ni * 16 + l15;
        int h = cn >> 6, d = cn & 63;
        float bias = bv[cn];
        int gm0 = rowBase + wr + mi * 16 + quad * 4;
        int b = gm0 >> 11, t = gm0 & 2047;
        us4_t o4;
#pragma unroll
        for (int r = 0; r < 4; ++r) o4[r] = f2bf(acc[mi][ni][r] + bias);
        *(us4_t*)&Vtb[((size_t)(b * NH + h) * HD + d) * SEQ + t] = o4;
      }
    }
  }
}

// ---------------- flash attention v10 (unchanged from R11): 4-wave blocks -------
__global__ __launch_bounds__(256, 4) void flash_attn10(
    const unsigned short* __restrict__ Qb, const unsigned short* __restrict__ Kb,
    const unsigned short* __restrict__ Vt, const float* __restrict__ biasArr,
    const unsigned short* __restrict__ maskB, const float* __restrict__ betaP,
    unsigned short* __restrict__ attn) {
  __shared__ __align__(16) char smem[24576];
  unsigned short* Klds = (unsigned short*)smem;            // [4096] = 8 KB
  unsigned short* Vlds = (unsigned short*)(smem + 8192);   // [4096]
  unsigned short* Plds = (unsigned short*)(smem + 16384);  // [4 wave][1024]
  const int tid = threadIdx.x;
  const int w = tid >> 6, lane = tid & 63;   // w = q-subtile
  const int quad = lane >> 4, l15 = lane & 15;
  const int id = blockIdx.x;
  const int h = id >> 6;            // 0..11
  const int qb = id & 63;
  const int qt = qb >> 1, b = qb & 1;   // XCD = qb%8: 12 heads of (qt,b) share an XCD
  const int bh = b * NH + h;
  const int q0 = qt * 64;
  const int q = q0 + w * 16 + l15;  // this lane's query
  const float betav2 = betaP[0] * LOG2E;
  const int sw = l15 & 7;

  const unsigned short* qbase = Qb + ((size_t)bh * SEQ + q) * HD;
  bf8_t qf[2];
  qf[0] = *(const bf8_t*)(qbase + quad * 8);
  qf[1] = *(const bf8_t*)(qbase + 32 + quad * 8);

  union { us8_t u; bf8_t b; } ou;
#pragma unroll
  for (int i = 0; i < 8; ++i) ou.u[i] = 0x3F80;
  const bf8_t ones = ou.b;

  f4_t Oacc[4] = {};   // unnormalized O^T partial
  f4_t Lacc = {};      // every element converges to l (ones-MFMA)

  unsigned short* Pw = Plds + w * 1024;
  const unsigned short* KgBase = Kb + (size_t)bh * SEQ * HD;
  const unsigned short* VtG = Vt + (size_t)bh * HD * SEQ;
  const unsigned short* maskRow = maskB + ((size_t)b * SEQ + q) * SEQ;
  const float* biasRow = biasArr + (size_t)bh * SEQ;

  const int e0 = tid * 8;
  const int r0 = e0 >> 6, c0 = e0 & 63;
  const int e1 = 2048 + e0;
  const int r1 = e1 >> 6, c1 = e1 & 63;
  const int ph0 = r0 * 64 + ((((c0 >> 3) ^ (r0 & 7))) << 3);
  const int ph1 = r1 * 64 + ((((c1 >> 3) ^ (r1 & 7))) << 3);

  us8_t kreg[2], vreg[2];
  uint2 mregu[4];
  kreg[0] = *(const us8_t*)(KgBase + (size_t)r0 * HD + c0);
  kreg[1] = *(const us8_t*)(KgBase + (size_t)r1 * HD + c1);
  vreg[0] = *(const us8_t*)(VtG + (size_t)r0 * SEQ + c0);
  vreg[1] = *(const us8_t*)(VtG + (size_t)r1 * SEQ + c1);
#pragma unroll
  for (int st = 0; st < 4; ++st)
    mregu[st] = *(const uint2*)&maskRow[st * 16 + quad * 4];

  for (int it = 0; it < 32; ++it) {
    const int soff = it * 64;
    __syncthreads();
    *(us8_t*)&Klds[ph0] = kreg[0];
    *(us8_t*)&Klds[ph1] = kreg[1];
    *(us8_t*)&Vlds[ph0] = vreg[0];
    *(us8_t*)&Vlds[ph1] = vreg[1];
    __syncthreads();

    float4 bb[4];
#pragma unroll
    for (int st = 0; st < 4; ++st) {
      float4 b4 = *(const float4*)&biasRow[soff + st * 16 + quad * 4];
      bb[st].x = fmaf(betav2, b4.x, -MSHIFT);
      bb[st].y = fmaf(betav2, b4.y, -MSHIFT);
      bb[st].z = fmaf(betav2, b4.z, -MSHIFT);
      bb[st].w = fmaf(betav2, b4.w, -MSHIFT);
    }

    f4_t sacc[4];
#pragma unroll
    for (int st = 0; st < 4; ++st) {
      sacc[st] = (f4_t){0.f, 0.f, 0.f, 0.f};
#pragma unroll
      for (int ks = 0; ks < 2; ++ks) {
        bf8_t kf = *(const bf8_t*)&Klds[(st * 16 + l15) * 64 + (((ks * 4 + quad) ^ sw) << 3)];
        sacc[st] = __builtin_amdgcn_mfma_f32_16x16x32_bf16(kf, qf[ks], sacc[st], 0, 0, 0);
      }
    }

#pragma unroll
    for (int st = 0; st < 4; ++st) {
      sacc[st][0] += fmaf(LOG2E, bflo(mregu[st].x), bb[st].x);
      sacc[st][1] += fmaf(LOG2E, bfhi(mregu[st].x), bb[st].y);
      sacc[st][2] += fmaf(LOG2E, bflo(mregu[st].y), bb[st].z);
      sacc[st][3] += fmaf(LOG2E, bfhi(mregu[st].y), bb[st].w);
    }

    if (it < 31) {
      const int nf = soff + 64;
      kreg[0] = *(const us8_t*)(KgBase + (size_t)(nf + r0) * HD + c0);
      kreg[1] = *(const us8_t*)(KgBase + (size_t)(nf + r1) * HD + c1);
      vreg[0] = *(const us8_t*)(VtG + (size_t)r0 * SEQ + nf + c0);
      vreg[1] = *(const us8_t*)(VtG + (size_t)r1 * SEQ + nf + c1);
#pragma unroll
      for (int st = 0; st < 4; ++st)
        mregu[st] = *(const uint2*)&maskRow[nf + st * 16 + quad * 4];
    }

#pragma unroll
    for (int st = 0; st < 4; ++st)
#pragma unroll
      for (int r = 0; r < 4; ++r) sacc[st][r] = ex2(sacc[st][r]);

#pragma unroll
    for (int st = 0; st < 4; ++st) {
      uint2 pp;
      pp.x = pk2(sacc[st][0], sacc[st][1]);
      pp.y = pk2(sacc[st][2], sacc[st][3]);
      int col = st * 16 + quad * 4;
      int addr = l15 * 64 + ((((col >> 3) ^ sw)) << 3) + (col & 7);
      *(uint2*)&Pw[addr] = pp;
    }

#pragma unroll
    for (int ks = 0; ks < 2; ++ks) {
      bf8_t pf = *(const bf8_t*)&Pw[l15 * 64 + (((ks * 4 + quad) ^ sw) << 3)];
      Lacc = __builtin_amdgcn_mfma_f32_16x16x32_bf16(ones, pf, Lacc, 0, 0, 0);
#pragma unroll
      for (int dt = 0; dt < 4; ++dt) {
        bf8_t vf = *(const bf8_t*)&Vlds[(dt * 16 + l15) * 64 + (((ks * 4 + quad) ^ sw) << 3)];
        Oacc[dt] = __builtin_amdgcn_mfma_f32_16x16x32_bf16(vf, pf, Oacc[dt], 0, 0, 0);
      }
    }
  }

  float inv = 1.0f / Lacc[0];
  unsigned short* orow = attn + ((size_t)b * SEQ + q) * E + h * HD;
#pragma unroll
  for (int dt = 0; dt < 4; ++dt) {
    us4_t o4;
#pragma unroll
    for (int r = 0; r < 4; ++r) o4[r] = f2bf(Oacc[dt][r] * inv);
    *(us4_t*)&orow[dt * 16 + quad * 4] = o4;
  }
}

// ---------------- output projection GEMM -> fp32 out (64x64 tiles) ----------------
// grid (64, 12) = 768 blocks (3/CU). Wave = 32x32 region, acc[2][2].
__global__ __launch_bounds__(256) void gemm_out(
    const unsigned short* __restrict__ A, const unsigned short* __restrict__ Bw,
    const float* __restrict__ bo, float* __restrict__ out) {
  __shared__ unsigned short Alds[64 * 32];
  __shared__ unsigned short Blds[64 * 32];
  const int w = threadIdx.x >> 6, lane = threadIdx.x & 63;
  const int quad = lane >> 4, l15 = lane & 15;
  const int rowBase = blockIdx.x * 64;
  const int colBase = blockIdx.y * 64;
  const int wr = (w & 1) * 32, wc = (w >> 1) * 32;
  f4_t acc[2][2] = {};

  const int idxT = w * 512 + lane * 8;  // 1 chunk/wave for each of A, B (64x32)

  for (int k0 = 0; k0 < E; k0 += 32) {
    __syncthreads();
    {
      const unsigned short* ga = A + (size_t)(rowBase + (idxT >> 5)) * E + k0 + (idxT & 31);
      __builtin_amdgcn_global_load_lds((const __attribute__((address_space(1))) void*)ga,
          (__attribute__((address_space(3))) void*)&Alds[w * 512], 16, 0, 0);
      const unsigned short* gb = Bw + (size_t)(colBase + (idxT >> 5)) * E + k0 + (idxT & 31);
      __builtin_amdgcn_global_load_lds((const __attribute__((address_space(1))) void*)gb,
          (__attribute__((address_space(3))) void*)&Blds[w * 512], 16, 0, 0);
    }
    __builtin_amdgcn_s_waitcnt(0);
    __syncthreads();
    bf8_t af[2], bfr[2];
#pragma unroll
    for (int mi = 0; mi < 2; ++mi)
      af[mi] = *(const bf8_t*)&Alds[(wr + mi * 16 + l15) * 32 + quad * 8];
#pragma unroll
    for (int ni = 0; ni < 2; ++ni)
      bfr[ni] = *(const bf8_t*)&Blds[(wc + ni * 16 + l15) * 32 + quad * 8];
#pragma unroll
    for (int mi = 0; mi < 2; ++mi)
#pragma unroll
      for (int ni = 0; ni < 2; ++ni)
        acc[mi][ni] = __builtin_amdgcn_mfma_f32_16x16x32_bf16(af[mi], bfr[ni], acc[mi][ni], 0, 0, 0);
  }

#pragma unroll
  for (int mi = 0; mi < 2; ++mi) {
#pragma unroll
    for (int ni = 0; ni < 2; ++ni) {
      int gn = colBase + wc + ni * 16 + l15;
      float bias = bo[gn];
#pragma unroll
      for (int r = 0; r < 4; ++r) {
        int gm = rowBase + wr + mi * 16 + quad * 4 + r;
        out[(size_t)gm * E + gn] = acc[mi][ni][r] + bias;
      }
    }
  }
}

extern "C" void kernel_launch(void* const* d_in, const int* in_sizes, int n_in,
                              void* d_out, int out_size, void* d_ws, size_t ws_size,
                              hipStream_t stream) {
  const float* hidden = (const float*)d_in[0];
  const float* mask = (const float*)d_in[1];
  const float* abias = (const float*)d_in[2];
  const float* Wq = (const float*)d_in[3];
  const float* bq = (const float*)d_in[4];
  const float* Wk = (const float*)d_in[5];
  const float* bk = (const float*)d_in[6];
  const float* Wv = (const float*)d_in[7];
  const float* bv = (const float*)d_in[8];
  const float* Wo = (const float*)d_in[9];
  const float* bo = (const float*)d_in[10];
  const float* beta = (const float*)d_in[11];
  float* out = (float*)d_out;

  char* ws = (char*)d_ws;
  unsigned short* Xbf = (unsigned short*)(ws);
  unsigned short* Wqkv = (unsigned short*)(ws + 6291456);
  unsigned short* Wobf = (unsigned short*)(ws + 9830400);
  unsigned short* Qbuf = (unsigned short*)(ws + 11010048);
  unsigned short* Kbuf = (unsigned short*)(ws + 17301504);
  unsigned short* Vtb = (unsigned short*)(ws + 23592960);
  unsigned short* Maskbf = (unsigned short*)(ws + 29884416);  // 16.7 MB bytes
  unsigned short* Attn = Xbf;  // Xbf dead after gemm_qkv

  cvt_all<<<6784, 256, 0, stream>>>(hidden, Wq, Wk, Wv, Wo, mask, Xbf, Wqkv, Wobf, Maskbf);
  gemm_qkv<<<dim3(64, 18), 256, 0, stream>>>(Xbf, Wqkv, bq, bk, bv, Qbuf, Kbuf, Vtb);
  flash_attn10<<<768, 256, 0, stream>>>(Qbuf, Kbuf, Vtb, abias, Maskbf, beta, Attn);
  gemm_out<<<dim3(64, 12), 256, 0, stream>>>(Attn, Wobf, bo, out);
}

// Round 13
// 238.005 us; speedup vs baseline: 1.0564x; 1.0059x over previous
//
#include <hip/hip_runtime.h>
#include <hip/hip_bf16.h>

#define E 768
#define HD 64
#define NH 12
#define BSZ 2
#define SEQ 2048
#define M_ROWS (BSZ * SEQ)   // 4096
#define BH (BSZ * NH)        // 24

#define LOG2E 1.44269504f
#define QSCALE 0.18033688f   // 0.125 * log2e folded into Q
#define MSHIFT 16.0f         // fixed exponent shift (scores in log2 domain within +-16)

typedef float f4_t __attribute__((ext_vector_type(4)));
typedef __bf16 bf8_t __attribute__((ext_vector_type(8)));
typedef unsigned short us8_t __attribute__((ext_vector_type(8)));
typedef unsigned short us4_t __attribute__((ext_vector_type(4)));

__device__ inline unsigned short f2bf(float f) {
  union { float f; unsigned u; } v; v.f = f;
  unsigned u = v.u + 0x7FFFu + ((v.u >> 16) & 1u);
  return (unsigned short)(u >> 16);
}

__device__ inline float ex2(float x) { return __builtin_amdgcn_exp2f(x); }

// bf16 pair -> fp32 (low / high halves of a uint)
__device__ inline float bflo(unsigned u) { union { unsigned u; float f; } v; v.u = u << 16; return v.f; }
__device__ inline float bfhi(unsigned u) { union { unsigned u; float f; } v; v.u = u & 0xFFFF0000u; return v.f; }

// pack two fp32 -> two bf16 in one v_perm (round-half-up)
__device__ inline unsigned pk2(float a, float b) {
  union { float f; unsigned u; } ua, ub;
  ua.f = a; ub.f = b;
  return __builtin_amdgcn_perm(ub.u + 0x8000u, ua.u + 0x8000u, 0x07060302u);
}

// ---------------- fused fp32 -> bf16 convert: X, 4 weights, and the MASK -------
// blocks: [0,1536) X | [1536,2688) weights | [2688,6784) mask (8.39M elems)
__global__ __launch_bounds__(256) void cvt_all(
    const float* __restrict__ X, const float* __restrict__ Wq,
    const float* __restrict__ Wk, const float* __restrict__ Wv,
    const float* __restrict__ Wo, const float* __restrict__ mask,
    unsigned short* __restrict__ Xbf, unsigned short* __restrict__ Wqkv,
    unsigned short* __restrict__ Wobf, unsigned short* __restrict__ maskbf) {
  const int nW = E * E;  // 589824
  int id = blockIdx.x;
  const float* src;
  unsigned short* dst;
  float scale = 1.0f;
  int base;
  if (id < 1536) {
    src = X; dst = Xbf; base = id * 2048;
  } else if (id < 2688) {
    int r = id - 1536;
    int k = r / 288;
    int rb = r - k * 288;
    base = rb * 2048;
    if (k == 0)      { src = Wq; dst = Wqkv;          scale = QSCALE; }
    else if (k == 1) { src = Wk; dst = Wqkv + nW;     }
    else if (k == 2) { src = Wv; dst = Wqkv + 2 * nW; }
    else             { src = Wo; dst = Wobf;          }
  } else {
    src = mask; dst = maskbf; base = (id - 2688) * 2048;  // 4096 blocks = 8,388,608 elems
  }
  int i = base + threadIdx.x * 8;
  const float4* s = (const float4*)(src + i);
  float4 a = s[0], b = s[1];
  us8_t o;
  o[0] = f2bf(a.x * scale); o[1] = f2bf(a.y * scale);
  o[2] = f2bf(a.z * scale); o[3] = f2bf(a.w * scale);
  o[4] = f2bf(b.x * scale); o[5] = f2bf(b.y * scale);
  o[6] = f2bf(b.z * scale); o[7] = f2bf(b.w * scale);
  *(us8_t*)(dst + i) = o;
}

// ---------------- fused QKV GEMM: C = X @ Wqkv^T, 64x128 tiles ------
__global__ __launch_bounds__(256) void gemm_qkv(
    const unsigned short* __restrict__ A, const unsigned short* __restrict__ Bw,
    const float* __restrict__ bq, const float* __restrict__ bk, const float* __restrict__ bv,
    unsigned short* __restrict__ Qb, unsigned short* __restrict__ Kb,
    unsigned short* __restrict__ Vtb) {
  __shared__ unsigned short Alds[64 * 32];    // 4 KB
  __shared__ unsigned short Blds[128 * 32];   // 8 KB
  const int w = threadIdx.x >> 6, lane = threadIdx.x & 63;
  const int quad = lane >> 4, l15 = lane & 15;
  const int rowBase = blockIdx.x * 64;
  const int colBase = blockIdx.y * 128;
  const int wr = (w & 1) * 32, wc = (w >> 1) * 64;
  f4_t acc[2][4] = {};

  const int idxA = w * 512 + lane * 8;
  const int idx0 = (w * 2) * 512 + lane * 8;
  const int idx1 = (w * 2 + 1) * 512 + lane * 8;

  for (int k0 = 0; k0 < E; k0 += 32) {
    __syncthreads();
    {
      const unsigned short* ga = A + (size_t)(rowBase + (idxA >> 5)) * E + k0 + (idxA & 31);
      __builtin_amdgcn_global_load_lds((const __attribute__((address_space(1))) void*)ga,
          (__attribute__((address_space(3))) void*)&Alds[w * 512], 16, 0, 0);
    }
#pragma unroll
    for (int c = 0; c < 2; ++c) {
      int idx = (c == 0) ? idx0 : idx1;
      const unsigned short* gb = Bw + (size_t)(colBase + (idx >> 5)) * E + k0 + (idx & 31);
      __builtin_amdgcn_global_load_lds((const __attribute__((address_space(1))) void*)gb,
          (__attribute__((address_space(3))) void*)&Blds[(w * 2 + c) * 512], 16, 0, 0);
    }
    __builtin_amdgcn_s_waitcnt(0);
    __syncthreads();
    bf8_t af[2], bfr[4];
#pragma unroll
    for (int mi = 0; mi < 2; ++mi)
      af[mi] = *(const bf8_t*)&Alds[(wr + mi * 16 + l15) * 32 + quad * 8];
#pragma unroll
    for (int ni = 0; ni < 4; ++ni)
      bfr[ni] = *(const bf8_t*)&Blds[(wc + ni * 16 + l15) * 32 + quad * 8];
#pragma unroll
    for (int mi = 0; mi < 2; ++mi)
#pragma unroll
      for (int ni = 0; ni < 4; ++ni)
        acc[mi][ni] = __builtin_amdgcn_mfma_f32_16x16x32_bf16(af[mi], bfr[ni], acc[mi][ni], 0, 0, 0);
  }

  const int which = colBase / E;
  __syncthreads();
  if (which < 2) {
    const float* biasP = (which == 0) ? bq : bk;
    unsigned short* dst = (which == 0) ? Qb : Kb;
    const float bscale = (which == 0) ? QSCALE : 1.0f;
    const int cnBase = colBase - which * E + wc;
    const int h = cnBase >> 6;
    float biasv[4];
#pragma unroll
    for (int ni = 0; ni < 4; ++ni) biasv[ni] = biasP[cnBase + ni * 16 + l15] * bscale;
    unsigned short* T = Blds + w * 1024;
    const int row = lane >> 2, colE = (lane & 3) * 16;
#pragma unroll
    for (int mi = 0; mi < 2; ++mi) {
#pragma unroll
      for (int ni = 0; ni < 4; ++ni)
#pragma unroll
        for (int r = 0; r < 4; ++r)
          T[(quad * 4 + r) * 64 + ni * 16 + l15] = f2bf(acc[mi][ni][r] + biasv[ni]);
      us8_t o0 = *(const us8_t*)&T[row * 64 + colE];
      us8_t o1 = *(const us8_t*)&T[row * 64 + colE + 8];
      int gm = rowBase + wr + mi * 16 + row;
      int b = gm >> 11, t = gm & 2047;
      unsigned short* drow = dst + ((size_t)(b * NH + h) * SEQ + t) * HD;
      *(us8_t*)&drow[colE] = o0;
      *(us8_t*)&drow[colE + 8] = o1;
    }
  } else {
#pragma unroll
    for (int mi = 0; mi < 2; ++mi) {
#pragma unroll
      for (int ni = 0; ni < 4; ++ni) {
        int cn = colBase - 2 * E + wc + ni * 16 + l15;
        int h = cn >> 6, d = cn & 63;
        float bias = bv[cn];
        int gm0 = rowBase + wr + mi * 16 + quad * 4;
        int b = gm0 >> 11, t = gm0 & 2047;
        us4_t o4;
#pragma unroll
        for (int r = 0; r < 4; ++r) o4[r] = f2bf(acc[mi][ni][r] + bias);
        *(us4_t*)&Vtb[((size_t)(b * NH + h) * HD + d) * SEQ + t] = o4;
      }
    }
  }
}

// ---------------- flash attention v11: asm-forced K/V prefetch ----------------
// v10 structure (4-wave blocks, fixed-shift softmax, ones-MFMA l, bf16 mask,
// XCD swizzle) + the K/V staging loads issued via inline-asm global_load_dwordx4
// one iteration ahead. asm volatile cannot be sunk across the barrier (5 prior
// HIP-level prefetch attempts were all sunk: VGPR_Count 56-60 each time). The
// s_waitcnt vmcnt(0) asm at loop top carries "+v" deps on the prefetch regs so
// the LDS writes are ordered after the wait.
__global__ __launch_bounds__(256, 4) void flash_attn11(
    const unsigned short* __restrict__ Qb, const unsigned short* __restrict__ Kb,
    const unsigned short* __restrict__ Vt, const float* __restrict__ biasArr,
    const unsigned short* __restrict__ maskB, const float* __restrict__ betaP,
    unsigned short* __restrict__ attn) {
  __shared__ __align__(16) char smem[24576];
  unsigned short* Klds = (unsigned short*)smem;            // [4096] = 8 KB
  unsigned short* Vlds = (unsigned short*)(smem + 8192);   // [4096]
  unsigned short* Plds = (unsigned short*)(smem + 16384);  // [4 wave][1024]
  const int tid = threadIdx.x;
  const int w = tid >> 6, lane = tid & 63;   // w = q-subtile
  const int quad = lane >> 4, l15 = lane & 15;
  const int id = blockIdx.x;
  const int h = id >> 6;            // 0..11
  const int qb = id & 63;
  const int qt = qb >> 1, b = qb & 1;   // XCD = qb%8
  const int bh = b * NH + h;
  const int q0 = qt * 64;
  const int q = q0 + w * 16 + l15;  // this lane's query
  const float betav2 = betaP[0] * LOG2E;
  const int sw = l15 & 7;

  const unsigned short* qbase = Qb + ((size_t)bh * SEQ + q) * HD;
  bf8_t qf[2];
  qf[0] = *(const bf8_t*)(qbase + quad * 8);
  qf[1] = *(const bf8_t*)(qbase + 32 + quad * 8);

  union { us8_t u; bf8_t b; } ou;
#pragma unroll
  for (int i = 0; i < 8; ++i) ou.u[i] = 0x3F80;
  const bf8_t ones = ou.b;

  f4_t Oacc[4] = {};   // unnormalized O^T partial
  f4_t Lacc = {};      // every element converges to l (ones-MFMA)

  unsigned short* Pw = Plds + w * 1024;
  const unsigned short* KgBase = Kb + (size_t)bh * SEQ * HD;
  const unsigned short* VtG = Vt + (size_t)bh * HD * SEQ;
  const unsigned short* maskRow = maskB + ((size_t)b * SEQ + q) * SEQ;
  const float* biasRow = biasArr + (size_t)bh * SEQ;

  const int e0 = tid * 8;
  const int r0 = e0 >> 6, c0 = e0 & 63;
  const int e1 = 2048 + e0;
  const int r1 = e1 >> 6, c1 = e1 & 63;
  const int ph0 = r0 * 64 + ((((c0 >> 3) ^ (r0 & 7))) << 3);
  const int ph1 = r1 * 64 + ((((c1 >> 3) ^ (r1 & 7))) << 3);

  us8_t kreg0, kreg1, vreg0, vreg1;
  uint2 mregu[4];

  // ---- prologue: asm-issue K/V loads for tile 0; mask prefetch (compiler) ----
  {
    const unsigned short* pk0 = KgBase + (size_t)r0 * HD + c0;
    const unsigned short* pk1 = KgBase + (size_t)r1 * HD + c1;
    const unsigned short* pv0 = VtG + (size_t)r0 * SEQ + c0;
    const unsigned short* pv1 = VtG + (size_t)r1 * SEQ + c1;
    asm volatile(
        "global_load_dwordx4 %0, %4, off\n\t"
        "global_load_dwordx4 %1, %5, off\n\t"
        "global_load_dwordx4 %2, %6, off\n\t"
        "global_load_dwordx4 %3, %7, off"
        : "=&v"(kreg0), "=&v"(kreg1), "=&v"(vreg0), "=&v"(vreg1)
        : "v"(pk0), "v"(pk1), "v"(pv0), "v"(pv1));
  }
#pragma unroll
  for (int st = 0; st < 4; ++st)
    mregu[st] = *(const uint2*)&maskRow[st * 16 + quad * 4];

  for (int it = 0; it < 32; ++it) {
    const int soff = it * 64;
    // wait for the asm prefetch (deps order the LDS writes after this)
    asm volatile("s_waitcnt vmcnt(0)"
                 : "+v"(kreg0), "+v"(kreg1), "+v"(vreg0), "+v"(vreg1));
    __syncthreads();  // previous iter's frag reads complete
    *(us8_t*)&Klds[ph0] = kreg0;
    *(us8_t*)&Klds[ph1] = kreg1;
    *(us8_t*)&Vlds[ph0] = vreg0;
    *(us8_t*)&Vlds[ph1] = vreg1;
    __syncthreads();  // publish staging

    // bias (compiler load, consumed before the asm issue below)
    float4 bb[4];
#pragma unroll
    for (int st = 0; st < 4; ++st) {
      float4 b4 = *(const float4*)&biasRow[soff + st * 16 + quad * 4];
      bb[st].x = fmaf(betav2, b4.x, -MSHIFT);
      bb[st].y = fmaf(betav2, b4.y, -MSHIFT);
      bb[st].z = fmaf(betav2, b4.z, -MSHIFT);
      bb[st].w = fmaf(betav2, b4.w, -MSHIFT);
    }

    // S^T = K Q^T (log2 domain)
    f4_t sacc[4];
#pragma unroll
    for (int st = 0; st < 4; ++st) {
      sacc[st] = (f4_t){0.f, 0.f, 0.f, 0.f};
#pragma unroll
      for (int ks = 0; ks < 2; ++ks) {
        bf8_t kf = *(const bf8_t*)&Klds[(st * 16 + l15) * 64 + (((ks * 4 + quad) ^ sw) << 3)];
        sacc[st] = __builtin_amdgcn_mfma_f32_16x16x32_bf16(kf, qf[ks], sacc[st], 0, 0, 0);
      }
    }

    // fold bias + mask (consumes mregu -> frees it for the next prefetch)
#pragma unroll
    for (int st = 0; st < 4; ++st) {
      sacc[st][0] += fmaf(LOG2E, bflo(mregu[st].x), bb[st].x);
      sacc[st][1] += fmaf(LOG2E, bfhi(mregu[st].x), bb[st].y);
      sacc[st][2] += fmaf(LOG2E, bflo(mregu[st].y), bb[st].z);
      sacc[st][3] += fmaf(LOG2E, bfhi(mregu[st].y), bb[st].w);
    }

    // ---- asm-issue K/V loads for it+1 (un-sinkable; consumed at next top) ----
    if (it < 31) {
      const int nf = soff + 64;
      const unsigned short* pk0 = KgBase + (size_t)(nf + r0) * HD + c0;
      const unsigned short* pk1 = KgBase + (size_t)(nf + r1) * HD + c1;
      const unsigned short* pv0 = VtG + (size_t)r0 * SEQ + nf + c0;
      const unsigned short* pv1 = VtG + (size_t)r1 * SEQ + nf + c1;
      asm volatile(
          "global_load_dwordx4 %0, %4, off\n\t"
          "global_load_dwordx4 %1, %5, off\n\t"
          "global_load_dwordx4 %2, %6, off\n\t"
          "global_load_dwordx4 %3, %7, off"
          : "=&v"(kreg0), "=&v"(kreg1), "=&v"(vreg0), "=&v"(vreg1)
          : "v"(pk0), "v"(pk1), "v"(pv0), "v"(pv1));
      // mask prefetch (compiler-managed; sunk at worst to use site)
#pragma unroll
      for (int st = 0; st < 4; ++st)
        mregu[st] = *(const uint2*)&maskRow[nf + st * 16 + quad * 4];
    }

    // p = exp2(s)
#pragma unroll
    for (int st = 0; st < 4; ++st)
#pragma unroll
      for (int r = 0; r < 4; ++r) sacc[st][r] = ex2(sacc[st][r]);

    // pack P + per-wave LDS round-trip (swizzled; wave-private, no barrier)
#pragma unroll
    for (int st = 0; st < 4; ++st) {
      uint2 pp;
      pp.x = pk2(sacc[st][0], sacc[st][1]);
      pp.y = pk2(sacc[st][2], sacc[st][3]);
      int col = st * 16 + quad * 4;
      int addr = l15 * 64 + ((((col >> 3) ^ sw)) << 3) + (col & 7);
      *(uint2*)&Pw[addr] = pp;
    }

    // O^T += V^T P^T ; l += ones x P^T
#pragma unroll
    for (int ks = 0; ks < 2; ++ks) {
      bf8_t pf = *(const bf8_t*)&Pw[l15 * 64 + (((ks * 4 + quad) ^ sw) << 3)];
      Lacc = __builtin_amdgcn_mfma_f32_16x16x32_bf16(ones, pf, Lacc, 0, 0, 0);
#pragma unroll
      for (int dt = 0; dt < 4; ++dt) {
        bf8_t vf = *(const bf8_t*)&Vlds[(dt * 16 + l15) * 64 + (((ks * 4 + quad) ^ sw) << 3)];
        Oacc[dt] = __builtin_amdgcn_mfma_f32_16x16x32_bf16(vf, pf, Oacc[dt], 0, 0, 0);
      }
    }
  }

  float inv = 1.0f / Lacc[0];
  unsigned short* orow = attn + ((size_t)b * SEQ + q) * E + h * HD;
#pragma unroll
  for (int dt = 0; dt < 4; ++dt) {
    us4_t o4;
#pragma unroll
    for (int r = 0; r < 4; ++r) o4[r] = f2bf(Oacc[dt][r] * inv);
    *(us4_t*)&orow[dt * 16 + quad * 4] = o4;
  }
}

// ---------------- output projection GEMM -> fp32 out (64x64 tiles) ----------------
__global__ __launch_bounds__(256) void gemm_out(
    const unsigned short* __restrict__ A, const unsigned short* __restrict__ Bw,
    const float* __restrict__ bo, float* __restrict__ out) {
  __shared__ unsigned short Alds[64 * 32];
  __shared__ unsigned short Blds[64 * 32];
  const int w = threadIdx.x >> 6, lane = threadIdx.x & 63;
  const int quad = lane >> 4, l15 = lane & 15;
  const int rowBase = blockIdx.x * 64;
  const int colBase = blockIdx.y * 64;
  const int wr = (w & 1) * 32, wc = (w >> 1) * 32;
  f4_t acc[2][2] = {};

  const int idxT = w * 512 + lane * 8;

  for (int k0 = 0; k0 < E; k0 += 32) {
    __syncthreads();
    {
      const unsigned short* ga = A + (size_t)(rowBase + (idxT >> 5)) * E + k0 + (idxT & 31);
      __builtin_amdgcn_global_load_lds((const __attribute__((address_space(1))) void*)ga,
          (__attribute__((address_space(3))) void*)&Alds[w * 512], 16, 0, 0);
      const unsigned short* gb = Bw + (size_t)(colBase + (idxT >> 5)) * E + k0 + (idxT & 31);
      __builtin_amdgcn_global_load_lds((const __attribute__((address_space(1))) void*)gb,
          (__attribute__((address_space(3))) void*)&Blds[w * 512], 16, 0, 0);
    }
    __builtin_amdgcn_s_waitcnt(0);
    __syncthreads();
    bf8_t af[2], bfr[2];
#pragma unroll
    for (int mi = 0; mi < 2; ++mi)
      af[mi] = *(const bf8_t*)&Alds[(wr + mi * 16 + l15) * 32 + quad * 8];
#pragma unroll
    for (int ni = 0; ni < 2; ++ni)
      bfr[ni] = *(const bf8_t*)&Blds[(wc + ni * 16 + l15) * 32 + quad * 8];
#pragma unroll
    for (int mi = 0; mi < 2; ++mi)
#pragma unroll
      for (int ni = 0; ni < 2; ++ni)
        acc[mi][ni] = __builtin_amdgcn_mfma_f32_16x16x32_bf16(af[mi], bfr[ni], acc[mi][ni], 0, 0, 0);
  }

#pragma unroll
  for (int mi = 0; mi < 2; ++mi) {
#pragma unroll
    for (int ni = 0; ni < 2; ++ni) {
      int gn = colBase + wc + ni * 16 + l15;
      float bias = bo[gn];
#pragma unroll
      for (int r = 0; r < 4; ++r) {
        int gm = rowBase + wr + mi * 16 + quad * 4 + r;
        out[(size_t)gm * E + gn] = acc[mi][ni][r] + bias;
      }
    }
  }
}

extern "C" void kernel_launch(void* const* d_in, const int* in_sizes, int n_in,
                              void* d_out, int out_size, void* d_ws, size_t ws_size,
                              hipStream_t stream) {
  const float* hidden = (const float*)d_in[0];
  const float* mask = (const float*)d_in[1];
  const float* abias = (const float*)d_in[2];
  const float* Wq = (const float*)d_in[3];
  const float* bq = (const float*)d_in[4];
  const float* Wk = (const float*)d_in[5];
  const float* bk = (const float*)d_in[6];
  const float* Wv = (const float*)d_in[7];
  const float* bv = (const float*)d_in[8];
  const float* Wo = (const float*)d_in[9];
  const float* bo = (const float*)d_in[10];
  const float* beta = (const float*)d_in[11];
  float* out = (float*)d_out;

  char* ws = (char*)d_ws;
  unsigned short* Xbf = (unsigned short*)(ws);
  unsigned short* Wqkv = (unsigned short*)(ws + 6291456);
  unsigned short* Wobf = (unsigned short*)(ws + 9830400);
  unsigned short* Qbuf = (unsigned short*)(ws + 11010048);
  unsigned short* Kbuf = (unsigned short*)(ws + 17301504);
  unsigned short* Vtb = (unsigned short*)(ws + 23592960);
  unsigned short* Maskbf = (unsigned short*)(ws + 29884416);
  unsigned short* Attn = Xbf;  // Xbf dead after gemm_qkv

  cvt_all<<<6784, 256, 0, stream>>>(hidden, Wq, Wk, Wv, Wo, mask, Xbf, Wqkv, Wobf, Maskbf);
  gemm_qkv<<<dim3(64, 18), 256, 0, stream>>>(Xbf, Wqkv, bq, bk, bv, Qbuf, Kbuf, Vtb);
  flash_attn11<<<768, 256, 0, stream>>>(Qbuf, Kbuf, Vtb, abias, Maskbf, beta, Attn);
  gemm_out<<<dim3(64, 12), 256, 0, stream>>>(Attn, Wobf, bo, out);
}

// Round 15
// 225.547 us; speedup vs baseline: 1.1148x; 1.0552x over previous
//
#include <hip/hip_runtime.h>
#include <hip/hip_bf16.h>

#define E 768
#define HD 64
#define NH 12
#define BSZ 2
#define SEQ 2048
#define M_ROWS (BSZ * SEQ)   // 4096
#define BH (BSZ * NH)        // 24

#define LOG2E 1.44269504f
#define QSCALE 0.18033688f   // 0.125 * log2e folded into Q
#define MSHIFT 16.0f         // fixed exponent shift (scores in log2 domain within +-16)

typedef float f4_t __attribute__((ext_vector_type(4)));
typedef __bf16 bf8_t __attribute__((ext_vector_type(8)));
typedef unsigned short us8_t __attribute__((ext_vector_type(8)));
typedef unsigned short us4_t __attribute__((ext_vector_type(4)));

__device__ inline unsigned short f2bf(float f) {
  union { float f; unsigned u; } v; v.f = f;
  unsigned u = v.u + 0x7FFFu + ((v.u >> 16) & 1u);
  return (unsigned short)(u >> 16);
}

__device__ inline float ex2(float x) { return __builtin_amdgcn_exp2f(x); }

// bf16 pair -> fp32 (low / high halves of a uint)
__device__ inline float bflo(unsigned u) { union { unsigned u; float f; } v; v.u = u << 16; return v.f; }
__device__ inline float bfhi(unsigned u) { union { unsigned u; float f; } v; v.u = u & 0xFFFF0000u; return v.f; }

// pack two fp32 -> two bf16 in one v_perm (round-half-up)
__device__ inline unsigned pk2(float a, float b) {
  union { float f; unsigned u; } ua, ub;
  ua.f = a; ub.f = b;
  return __builtin_amdgcn_perm(ub.u + 0x8000u, ua.u + 0x8000u, 0x07060302u);
}

// ---------------- fused fp32 -> bf16 convert: X, 4 weights, and the MASK -------
// blocks: [0,1536) X | [1536,2688) weights | [2688,6784) mask (8.39M elems)
__global__ __launch_bounds__(256) void cvt_all(
    const float* __restrict__ X, const float* __restrict__ Wq,
    const float* __restrict__ Wk, const float* __restrict__ Wv,
    const float* __restrict__ Wo, const float* __restrict__ mask,
    unsigned short* __restrict__ Xbf, unsigned short* __restrict__ Wqkv,
    unsigned short* __restrict__ Wobf, unsigned short* __restrict__ maskbf) {
  const int nW = E * E;  // 589824
  int id = blockIdx.x;
  const float* src;
  unsigned short* dst;
  float scale = 1.0f;
  int base;
  if (id < 1536) {
    src = X; dst = Xbf; base = id * 2048;
  } else if (id < 2688) {
    int r = id - 1536;
    int k = r / 288;
    int rb = r - k * 288;
    base = rb * 2048;
    if (k == 0)      { src = Wq; dst = Wqkv;          scale = QSCALE; }
    else if (k == 1) { src = Wk; dst = Wqkv + nW;     }
    else if (k == 2) { src = Wv; dst = Wqkv + 2 * nW; }
    else             { src = Wo; dst = Wobf;          }
  } else {
    src = mask; dst = maskbf; base = (id - 2688) * 2048;
  }
  int i = base + threadIdx.x * 8;
  const float4* s = (const float4*)(src + i);
  float4 a = s[0], b = s[1];
  us8_t o;
  o[0] = f2bf(a.x * scale); o[1] = f2bf(a.y * scale);
  o[2] = f2bf(a.z * scale); o[3] = f2bf(a.w * scale);
  o[4] = f2bf(b.x * scale); o[5] = f2bf(b.y * scale);
  o[6] = f2bf(b.z * scale); o[7] = f2bf(b.w * scale);
  *(us8_t*)(dst + i) = o;
}

// ---------------- fused QKV GEMM: 64x128 tiles, BK=64, swizzled LDS ------
// 12 k-iterations (was 24). LDS XOR-swizzled at 16B-chunk granularity via
// per-lane DMA SOURCE permutation. R14 bug fixed: chunks/thread now matches
// tile size (A: 512 chunks -> 2/thread, B: 1024 chunks -> 4/thread).
__global__ __launch_bounds__(256) void gemm_qkv(
    const unsigned short* __restrict__ A, const unsigned short* __restrict__ Bw,
    const float* __restrict__ bq, const float* __restrict__ bk, const float* __restrict__ bv,
    unsigned short* __restrict__ Qb, unsigned short* __restrict__ Kb,
    unsigned short* __restrict__ Vtb) {
  __shared__ unsigned short Alds[64 * 64];    // 8 KB  (64 rows x 64 k, swizzled)
  __shared__ unsigned short Blds[128 * 64];   // 16 KB (128 rows x 64 k, swizzled)
  const int w = threadIdx.x >> 6, lane = threadIdx.x & 63;
  const int quad = lane >> 4, l15 = lane & 15;
  const int rowBase = blockIdx.x * 64;
  const int colBase = blockIdx.y * 128;
  const int wr = (w & 1) * 32, wc = (w >> 1) * 64;
  f4_t acc[2][4] = {};
  const int swz = l15 & 7;

  for (int k0 = 0; k0 < E; k0 += 64) {
    __syncthreads();
    // A: 512 chunks (64 rows x 8 chunks), 2 per thread
#pragma unroll
    for (int c = 0; c < 2; ++c) {
      int s = c * 256 + w * 64 + lane;
      int r = s >> 3, col = ((s & 7) ^ (r & 7)) * 8;
      const unsigned short* ga = A + (size_t)(rowBase + r) * E + k0 + col;
      __builtin_amdgcn_global_load_lds((const __attribute__((address_space(1))) void*)ga,
          (__attribute__((address_space(3))) void*)&Alds[c * 2048 + w * 512], 16, 0, 0);
    }
    // B: 1024 chunks (128 rows x 8 chunks), 4 per thread
#pragma unroll
    for (int c = 0; c < 4; ++c) {
      int s = c * 256 + w * 64 + lane;
      int r = s >> 3, col = ((s & 7) ^ (r & 7)) * 8;
      const unsigned short* gb = Bw + (size_t)(colBase + r) * E + k0 + col;
      __builtin_amdgcn_global_load_lds((const __attribute__((address_space(1))) void*)gb,
          (__attribute__((address_space(3))) void*)&Blds[c * 2048 + w * 512], 16, 0, 0);
    }
    __builtin_amdgcn_s_waitcnt(0);
    __syncthreads();
    bf8_t af[2][2], bfr[4][2];
#pragma unroll
    for (int mi = 0; mi < 2; ++mi)
#pragma unroll
      for (int ks = 0; ks < 2; ++ks)
        af[mi][ks] = *(const bf8_t*)&Alds[(wr + mi * 16 + l15) * 64 + (((ks * 4 + quad) ^ swz) << 3)];
#pragma unroll
    for (int ni = 0; ni < 4; ++ni)
#pragma unroll
      for (int ks = 0; ks < 2; ++ks)
        bfr[ni][ks] = *(const bf8_t*)&Blds[(wc + ni * 16 + l15) * 64 + (((ks * 4 + quad) ^ swz) << 3)];
#pragma unroll
    for (int ks = 0; ks < 2; ++ks)
#pragma unroll
      for (int mi = 0; mi < 2; ++mi)
#pragma unroll
        for (int ni = 0; ni < 4; ++ni)
          acc[mi][ni] = __builtin_amdgcn_mfma_f32_16x16x32_bf16(af[mi][ks], bfr[ni][ks], acc[mi][ni], 0, 0, 0);
  }

  const int which = colBase / E;
  __syncthreads();  // staging reads done; Blds reusable as transpose scratch
  if (which < 2) {
    const float* biasP = (which == 0) ? bq : bk;
    unsigned short* dst = (which == 0) ? Qb : Kb;
    const float bscale = (which == 0) ? QSCALE : 1.0f;
    const int cnBase = colBase - which * E + wc;  // multiple of 64 -> single head
    const int h = cnBase >> 6;
    float biasv[4];
#pragma unroll
    for (int ni = 0; ni < 4; ++ni) biasv[ni] = biasP[cnBase + ni * 16 + l15] * bscale;
    unsigned short* T = Blds + w * 1024;  // per-wave 16x64 bf16 scratch
    const int row = lane >> 2, colE = (lane & 3) * 16;
#pragma unroll
    for (int mi = 0; mi < 2; ++mi) {
#pragma unroll
      for (int ni = 0; ni < 4; ++ni)
#pragma unroll
        for (int r = 0; r < 4; ++r)
          T[(quad * 4 + r) * 64 + ni * 16 + l15] = f2bf(acc[mi][ni][r] + biasv[ni]);
      us8_t o0 = *(const us8_t*)&T[row * 64 + colE];
      us8_t o1 = *(const us8_t*)&T[row * 64 + colE + 8];
      int gm = rowBase + wr + mi * 16 + row;
      int b = gm >> 11, t = gm & 2047;
      unsigned short* drow = dst + ((size_t)(b * NH + h) * SEQ + t) * HD;
      *(us8_t*)&drow[colE] = o0;
      *(us8_t*)&drow[colE + 8] = o1;
    }
  } else {
    // V^T epilogue: [bh][d][t], 4 consecutive t per store
#pragma unroll
    for (int mi = 0; mi < 2; ++mi) {
#pragma unroll
      for (int ni = 0; ni < 4; ++ni) {
        int cn = colBase - 2 * E + wc + ni * 16 + l15;
        int h = cn >> 6, d = cn & 63;
        float bias = bv[cn];
        int gm0 = rowBase + wr + mi * 16 + quad * 4;
        int b = gm0 >> 11, t = gm0 & 2047;
        us4_t o4;
#pragma unroll
        for (int r = 0; r < 4; ++r) o4[r] = f2bf(acc[mi][ni][r] + bias);
        *(us4_t*)&Vtb[((size_t)(b * NH + h) * HD + d) * SEQ + t] = o4;
      }
    }
  }
}

// ---------------- flash attention v11 (unchanged from R13) ----------------
__global__ __launch_bounds__(256, 4) void flash_attn11(
    const unsigned short* __restrict__ Qb, const unsigned short* __restrict__ Kb,
    const unsigned short* __restrict__ Vt, const float* __restrict__ biasArr,
    const unsigned short* __restrict__ maskB, const float* __restrict__ betaP,
    unsigned short* __restrict__ attn) {
  __shared__ __align__(16) char smem[24576];
  unsigned short* Klds = (unsigned short*)smem;            // [4096] = 8 KB
  unsigned short* Vlds = (unsigned short*)(smem + 8192);   // [4096]
  unsigned short* Plds = (unsigned short*)(smem + 16384);  // [4 wave][1024]
  const int tid = threadIdx.x;
  const int w = tid >> 6, lane = tid & 63;   // w = q-subtile
  const int quad = lane >> 4, l15 = lane & 15;
  const int id = blockIdx.x;
  const int h = id >> 6;            // 0..11
  const int qb = id & 63;
  const int qt = qb >> 1, b = qb & 1;   // XCD = qb%8
  const int bh = b * NH + h;
  const int q0 = qt * 64;
  const int q = q0 + w * 16 + l15;  // this lane's query
  const float betav2 = betaP[0] * LOG2E;
  const int sw = l15 & 7;

  const unsigned short* qbase = Qb + ((size_t)bh * SEQ + q) * HD;
  bf8_t qf[2];
  qf[0] = *(const bf8_t*)(qbase + quad * 8);
  qf[1] = *(const bf8_t*)(qbase + 32 + quad * 8);

  union { us8_t u; bf8_t b; } ou;
#pragma unroll
  for (int i = 0; i < 8; ++i) ou.u[i] = 0x3F80;
  const bf8_t ones = ou.b;

  f4_t Oacc[4] = {};   // unnormalized O^T partial
  f4_t Lacc = {};      // every element converges to l (ones-MFMA)

  unsigned short* Pw = Plds + w * 1024;
  const unsigned short* KgBase = Kb + (size_t)bh * SEQ * HD;
  const unsigned short* VtG = Vt + (size_t)bh * HD * SEQ;
  const unsigned short* maskRow = maskB + ((size_t)b * SEQ + q) * SEQ;
  const float* biasRow = biasArr + (size_t)bh * SEQ;

  const int e0 = tid * 8;
  const int r0 = e0 >> 6, c0 = e0 & 63;
  const int e1 = 2048 + e0;
  const int r1 = e1 >> 6, c1 = e1 & 63;
  const int ph0 = r0 * 64 + ((((c0 >> 3) ^ (r0 & 7))) << 3);
  const int ph1 = r1 * 64 + ((((c1 >> 3) ^ (r1 & 7))) << 3);

  us8_t kreg0, kreg1, vreg0, vreg1;
  uint2 mregu[4];

  {
    const unsigned short* pk0 = KgBase + (size_t)r0 * HD + c0;
    const unsigned short* pk1 = KgBase + (size_t)r1 * HD + c1;
    const unsigned short* pv0 = VtG + (size_t)r0 * SEQ + c0;
    const unsigned short* pv1 = VtG + (size_t)r1 * SEQ + c1;
    asm volatile(
        "global_load_dwordx4 %0, %4, off\n\t"
        "global_load_dwordx4 %1, %5, off\n\t"
        "global_load_dwordx4 %2, %6, off\n\t"
        "global_load_dwordx4 %3, %7, off"
        : "=&v"(kreg0), "=&v"(kreg1), "=&v"(vreg0), "=&v"(vreg1)
        : "v"(pk0), "v"(pk1), "v"(pv0), "v"(pv1));
  }
#pragma unroll
  for (int st = 0; st < 4; ++st)
    mregu[st] = *(const uint2*)&maskRow[st * 16 + quad * 4];

  for (int it = 0; it < 32; ++it) {
    const int soff = it * 64;
    asm volatile("s_waitcnt vmcnt(0)"
                 : "+v"(kreg0), "+v"(kreg1), "+v"(vreg0), "+v"(vreg1));
    __syncthreads();
    *(us8_t*)&Klds[ph0] = kreg0;
    *(us8_t*)&Klds[ph1] = kreg1;
    *(us8_t*)&Vlds[ph0] = vreg0;
    *(us8_t*)&Vlds[ph1] = vreg1;
    __syncthreads();

    float4 bb[4];
#pragma unroll
    for (int st = 0; st < 4; ++st) {
      float4 b4 = *(const float4*)&biasRow[soff + st * 16 + quad * 4];
      bb[st].x = fmaf(betav2, b4.x, -MSHIFT);
      bb[st].y = fmaf(betav2, b4.y, -MSHIFT);
      bb[st].z = fmaf(betav2, b4.z, -MSHIFT);
      bb[st].w = fmaf(betav2, b4.w, -MSHIFT);
    }

    f4_t sacc[4];
#pragma unroll
    for (int st = 0; st < 4; ++st) {
      sacc[st] = (f4_t){0.f, 0.f, 0.f, 0.f};
#pragma unroll
      for (int ks = 0; ks < 2; ++ks) {
        bf8_t kf = *(const bf8_t*)&Klds[(st * 16 + l15) * 64 + (((ks * 4 + quad) ^ sw) << 3)];
        sacc[st] = __builtin_amdgcn_mfma_f32_16x16x32_bf16(kf, qf[ks], sacc[st], 0, 0, 0);
      }
    }

#pragma unroll
    for (int st = 0; st < 4; ++st) {
      sacc[st][0] += fmaf(LOG2E, bflo(mregu[st].x), bb[st].x);
      sacc[st][1] += fmaf(LOG2E, bfhi(mregu[st].x), bb[st].y);
      sacc[st][2] += fmaf(LOG2E, bflo(mregu[st].y), bb[st].z);
      sacc[st][3] += fmaf(LOG2E, bfhi(mregu[st].y), bb[st].w);
    }

    if (it < 31) {
      const int nf = soff + 64;
      const unsigned short* pk0 = KgBase + (size_t)(nf + r0) * HD + c0;
      const unsigned short* pk1 = KgBase + (size_t)(nf + r1) * HD + c1;
      const unsigned short* pv0 = VtG + (size_t)r0 * SEQ + nf + c0;
      const unsigned short* pv1 = VtG + (size_t)r1 * SEQ + nf + c1;
      asm volatile(
          "global_load_dwordx4 %0, %4, off\n\t"
          "global_load_dwordx4 %1, %5, off\n\t"
          "global_load_dwordx4 %2, %6, off\n\t"
          "global_load_dwordx4 %3, %7, off"
          : "=&v"(kreg0), "=&v"(kreg1), "=&v"(vreg0), "=&v"(vreg1)
          : "v"(pk0), "v"(pk1), "v"(pv0), "v"(pv1));
#pragma unroll
      for (int st = 0; st < 4; ++st)
        mregu[st] = *(const uint2*)&maskRow[nf + st * 16 + quad * 4];
    }

#pragma unroll
    for (int st = 0; st < 4; ++st)
#pragma unroll
      for (int r = 0; r < 4; ++r) sacc[st][r] = ex2(sacc[st][r]);

#pragma unroll
    for (int st = 0; st < 4; ++st) {
      uint2 pp;
      pp.x = pk2(sacc[st][0], sacc[st][1]);
      pp.y = pk2(sacc[st][2], sacc[st][3]);
      int col = st * 16 + quad * 4;
      int addr = l15 * 64 + ((((col >> 3) ^ sw)) << 3) + (col & 7);
      *(uint2*)&Pw[addr] = pp;
    }

#pragma unroll
    for (int ks = 0; ks < 2; ++ks) {
      bf8_t pf = *(const bf8_t*)&Pw[l15 * 64 + (((ks * 4 + quad) ^ sw) << 3)];
      Lacc = __builtin_amdgcn_mfma_f32_16x16x32_bf16(ones, pf, Lacc, 0, 0, 0);
#pragma unroll
      for (int dt = 0; dt < 4; ++dt) {
        bf8_t vf = *(const bf8_t*)&Vlds[(dt * 16 + l15) * 64 + (((ks * 4 + quad) ^ sw) << 3)];
        Oacc[dt] = __builtin_amdgcn_mfma_f32_16x16x32_bf16(vf, pf, Oacc[dt], 0, 0, 0);
      }
    }
  }

  float inv = 1.0f / Lacc[0];
  unsigned short* orow = attn + ((size_t)b * SEQ + q) * E + h * HD;
#pragma unroll
  for (int dt = 0; dt < 4; ++dt) {
    us4_t o4;
#pragma unroll
    for (int r = 0; r < 4; ++r) o4[r] = f2bf(Oacc[dt][r] * inv);
    *(us4_t*)&orow[dt * 16 + quad * 4] = o4;
  }
}

// ---------------- output projection GEMM: 64x64 tiles, BK=64, swizzled --------
// R14 bug fixed: A,B each 512 chunks -> 2 chunks/thread.
__global__ __launch_bounds__(256) void gemm_out(
    const unsigned short* __restrict__ A, const unsigned short* __restrict__ Bw,
    const float* __restrict__ bo, float* __restrict__ out) {
  __shared__ unsigned short Alds[64 * 64];   // 8 KB
  __shared__ unsigned short Blds[64 * 64];   // 8 KB
  const int w = threadIdx.x >> 6, lane = threadIdx.x & 63;
  const int quad = lane >> 4, l15 = lane & 15;
  const int rowBase = blockIdx.x * 64;
  const int colBase = blockIdx.y * 64;
  const int wr = (w & 1) * 32, wc = (w >> 1) * 32;
  f4_t acc[2][2] = {};
  const int swz = l15 & 7;

  for (int k0 = 0; k0 < E; k0 += 64) {
    __syncthreads();
#pragma unroll
    for (int c = 0; c < 2; ++c) {
      int s = c * 256 + w * 64 + lane;
      int r = s >> 3, col = ((s & 7) ^ (r & 7)) * 8;
      const unsigned short* ga = A + (size_t)(rowBase + r) * E + k0 + col;
      __builtin_amdgcn_global_load_lds((const __attribute__((address_space(1))) void*)ga,
          (__attribute__((address_space(3))) void*)&Alds[c * 2048 + w * 512], 16, 0, 0);
      const unsigned short* gb = Bw + (size_t)(colBase + r) * E + k0 + col;
      __builtin_amdgcn_global_load_lds((const __attribute__((address_space(1))) void*)gb,
          (__attribute__((address_space(3))) void*)&Blds[c * 2048 + w * 512], 16, 0, 0);
    }
    __builtin_amdgcn_s_waitcnt(0);
    __syncthreads();
    bf8_t af[2][2], bfr[2][2];
#pragma unroll
    for (int mi = 0; mi < 2; ++mi)
#pragma unroll
      for (int ks = 0; ks < 2; ++ks)
        af[mi][ks] = *(const bf8_t*)&Alds[(wr + mi * 16 + l15) * 64 + (((ks * 4 + quad) ^ swz) << 3)];
#pragma unroll
    for (int ni = 0; ni < 2; ++ni)
#pragma unroll
      for (int ks = 0; ks < 2; ++ks)
        bfr[ni][ks] = *(const bf8_t*)&Blds[(wc + ni * 16 + l15) * 64 + (((ks * 4 + quad) ^ swz) << 3)];
#pragma unroll
    for (int ks = 0; ks < 2; ++ks)
#pragma unroll
      for (int mi = 0; mi < 2; ++mi)
#pragma unroll
        for (int ni = 0; ni < 2; ++ni)
          acc[mi][ni] = __builtin_amdgcn_mfma_f32_16x16x32_bf16(af[mi][ks], bfr[ni][ks], acc[mi][ni], 0, 0, 0);
  }

#pragma unroll
  for (int mi = 0; mi < 2; ++mi) {
#pragma unroll
    for (int ni = 0; ni < 2; ++ni) {
      int gn = colBase + wc + ni * 16 + l15;
      float bias = bo[gn];
#pragma unroll
      for (int r = 0; r < 4; ++r) {
        int gm = rowBase + wr + mi * 16 + quad * 4 + r;
        out[(size_t)gm * E + gn] = acc[mi][ni][r] + bias;
      }
    }
  }
}

extern "C" void kernel_launch(void* const* d_in, const int* in_sizes, int n_in,
                              void* d_out, int out_size, void* d_ws, size_t ws_size,
                              hipStream_t stream) {
  const float* hidden = (const float*)d_in[0];
  const float* mask = (const float*)d_in[1];
  const float* abias = (const float*)d_in[2];
  const float* Wq = (const float*)d_in[3];
  const float* bq = (const float*)d_in[4];
  const float* Wk = (const float*)d_in[5];
  const float* bk = (const float*)d_in[6];
  const float* Wv = (const float*)d_in[7];
  const float* bv = (const float*)d_in[8];
  const float* Wo = (const float*)d_in[9];
  const float* bo = (const float*)d_in[10];
  const float* beta = (const float*)d_in[11];
  float* out = (float*)d_out;

  char* ws = (char*)d_ws;
  unsigned short* Xbf = (unsigned short*)(ws);
  unsigned short* Wqkv = (unsigned short*)(ws + 6291456);
  unsigned short* Wobf = (unsigned short*)(ws + 9830400);
  unsigned short* Qbuf = (unsigned short*)(ws + 11010048);
  unsigned short* Kbuf = (unsigned short*)(ws + 17301504);
  unsigned short* Vtb = (unsigned short*)(ws + 23592960);
  unsigned short* Maskbf = (unsigned short*)(ws + 29884416);
  unsigned short* Attn = Xbf;  // Xbf dead after gemm_qkv

  cvt_all<<<6784, 256, 0, stream>>>(hidden, Wq, Wk, Wv, Wo, mask, Xbf, Wqkv, Wobf, Maskbf);
  gemm_qkv<<<dim3(64, 18), 256, 0, stream>>>(Xbf, Wqkv, bq, bk, bv, Qbuf, Kbuf, Vtb);
  flash_attn11<<<768, 256, 0, stream>>>(Qbuf, Kbuf, Vtb, abias, Maskbf, beta, Attn);
  gemm_out<<<dim3(64, 12), 256, 0, stream>>>(Attn, Wobf, bo, out);
}